// Round 1
// baseline (260.830 us; speedup 1.0000x reference)
//
#include <hip/hip_runtime.h>
#include <hip/hip_bf16.h>
#include <stdint.h>

#define C_INQ 256
#define CHQ 32
#define SDEP 128
#define NRES 256
#define CZQ 128

typedef __bf16 v8bf __attribute__((ext_vector_type(8)));
typedef __bf16 v4bf __attribute__((ext_vector_type(4)));
typedef float v16f __attribute__((ext_vector_type(16)));
typedef float v4f __attribute__((ext_vector_type(4)));

__device__ __forceinline__ void load_lds16(const void* g, void* l) {
  __builtin_amdgcn_global_load_lds(
      (const __attribute__((address_space(1))) void*)(uintptr_t)g,
      (__attribute__((address_space(3))) void*)(uintptr_t)l,
      16, 0, 0);
}

// ---------------- Kernel 1: LayerNorm -> xhat (bf16) ----------------
// one wave per (s,i) row; grid 8192 x 256
__global__ __launch_bounds__(256) void ln_kernel(
    const float* __restrict__ msa, const float* __restrict__ lnw,
    const float* __restrict__ lnb, __bf16* __restrict__ xh)
{
  const int wave = threadIdx.x >> 6, lane = threadIdx.x & 63;
  const int row = blockIdx.x * 4 + wave;          // s*256+i
  float4 x = ((const float4*)(msa + (size_t)row * C_INQ))[lane];
  float s1 = x.x + x.y + x.z + x.w;
  float s2 = x.x * x.x + x.y * x.y + x.z * x.z + x.w * x.w;
  #pragma unroll
  for (int o = 1; o < 64; o <<= 1) {
    s1 += __shfl_xor(s1, o);
    s2 += __shfl_xor(s2, o);
  }
  float mu = s1 * (1.f / 256.f);
  float var = s2 * (1.f / 256.f) - mu * mu;
  float rs = rsqrtf(var + 1e-5f);
  float4 w = ((const float4*)lnw)[lane];
  float4 b = ((const float4*)lnb)[lane];
  v4bf o;
  o[0] = (__bf16)((x.x - mu) * rs * w.x + b.x);
  o[1] = (__bf16)((x.y - mu) * rs * w.y + b.y);
  o[2] = (__bf16)((x.z - mu) * rs * w.z + b.z);
  o[3] = (__bf16)((x.w - mu) * rs * w.w + b.w);
  *(v4bf*)(xh + (size_t)row * C_INQ + lane * 4) = o;
}

// ---------------- Kernel 2: prep (rnorm, wo^T bf16, wl|wr ^T bf16) ----
// grid 832 x 256
__global__ __launch_bounds__(256) void prep_kernel(
    const float* __restrict__ mask, const float* __restrict__ wo,
    const float* __restrict__ wl, const float* __restrict__ wr,
    float* __restrict__ rnorm, __bf16* __restrict__ wot,
    __bf16* __restrict__ wcat)
{
  const int b = blockIdx.x, t = threadIdx.x;
  if (b < 256) {
    float acc = 0.f;
    for (int s = 0; s < SDEP; ++s)
      acc += mask[s * NRES + b] * mask[s * NRES + t];
    rnorm[b * NRES + t] = 1.f / fmaxf(acc, 1.f);
  } else if (b < 768) {
    int idx = (b - 256) * 256 + t;   // 0..131071: wot[z][cd] = wo[cd][z]
    int z = idx >> 10, cd = idx & 1023;
    wot[idx] = (__bf16)wo[cd * CZQ + z];
  } else {
    int idx = (b - 768) * 256 + t;   // 0..16383: wcat[n][k]
    int n = idx >> 8, k = idx & 255;
    const float* w = (n >= 32) ? wr : wl;
    wcat[idx] = (__bf16)w[k * CHQ + (n & 31)];
  }
}

// ---------------- Kernel 3: projections via MFMA ---------------------
// [32768,256] @ [256,64] -> At[ic][s], Bt[jd][s] (bf16, masked, +bias)
// grid 256 x 256; each wave: 32 rows
__global__ __launch_bounds__(256) void proj_kernel(
    const __bf16* __restrict__ xh, const __bf16* __restrict__ wcat,
    const float* __restrict__ bl, const float* __restrict__ br,
    const float* __restrict__ mask,
    __bf16* __restrict__ At, __bf16* __restrict__ Bt)
{
  const int wave = threadIdx.x >> 6, lane = threadIdx.x & 63;
  const int half = lane >> 5, l31 = lane & 31;
  const int m0 = blockIdx.x * 128 + wave * 32;
  const int mrow = m0 + l31;
  const int kb = half * 8;

  v16f acc0, acc1;
  #pragma unroll
  for (int r = 0; r < 16; ++r) { acc0[r] = 0.f; acc1[r] = 0.f; }

  #pragma unroll
  for (int ks = 0; ks < 16; ++ks) {
    v8bf a  = *(const v8bf*)(xh + (size_t)mrow * 256 + ks * 16 + kb);
    v8bf b0 = *(const v8bf*)(wcat + l31 * 256 + ks * 16 + kb);
    v8bf b1 = *(const v8bf*)(wcat + (32 + l31) * 256 + ks * 16 + kb);
    acc0 = __builtin_amdgcn_mfma_f32_32x32x16_bf16(a, b0, acc0, 0, 0, 0);
    acc1 = __builtin_amdgcn_mfma_f32_32x32x16_bf16(a, b1, acc1, 0, 0, 0);
  }

  const int c = l31;
  const float bA = bl[c], bB = br[c];
  #pragma unroll
  for (int r = 0; r < 16; ++r) {
    int rowi = (r & 3) + 8 * (r >> 2) + 4 * half;   // 0..31
    int m = m0 + rowi;                              // s*256+i
    float mv = mask[m];
    int i = m & 255, s = m >> 8;
    At[(i * CHQ + c) * SDEP + s] = (__bf16)((acc0[r] + bA) * mv);
    Bt[(i * CHQ + c) * SDEP + s] = (__bf16)((acc1[r] + bB) * mv);
  }
}

// ---------------- Kernel 4: fused outer-product-mean + out proj ------
// grid (64 j-tiles, 64 i-tiles) x 256 threads
__global__ __launch_bounds__(256) void outer_kernel(
    const __bf16* __restrict__ At, const __bf16* __restrict__ Bt,
    const float* __restrict__ rnorm, const __bf16* __restrict__ wot,
    const float* __restrict__ bo, float* __restrict__ out)
{
  __shared__ char smem[65536];
  __bf16* As = (__bf16*)smem;            // [128][128] 16B-chunk xor-swizzled
  __bf16* Bs = (__bf16*)(smem + 32768);
  __bf16* Ps = (__bf16*)smem;            // [16][1032] reused after barrier

  const int tid = threadIdx.x;
  const int wave = tid >> 6, lane = tid & 63;
  const int half = lane >> 5, l31 = lane & 31;
  const int bx = blockIdx.x;  // j tile (4 j's)
  const int by = blockIdx.y;  // i tile (4 i's)

  const char* Ag = (const char*)(At + (size_t)by * 128 * 128);
  const char* Bg = (const char*)(Bt + (size_t)bx * 128 * 128);

  // stage 32KB A + 32KB B, swizzle: LDS[m][cc] = G[m][cc ^ (m&15)]
  #pragma unroll
  for (int r = 0; r < 8; ++r) {
    int off = r * 4096 + tid * 16;        // LDS byte offset
    int m = off >> 8;
    int cc = (off >> 4) & 15;
    int gb = m * 256 + ((cc ^ (m & 15)) << 4);
    load_lds16(Ag + gb, smem + off);
    load_lds16(Bg + gb, smem + 32768 + off);
  }
  asm volatile("s_waitcnt vmcnt(0)" ::: "memory");
  __syncthreads();

  // GEMM1: C[128x128] = At_tile^ * Bt_tile, K=128
  const int wm = wave & 1, wn = wave >> 1;
  v16f acc[2][2];
  #pragma unroll
  for (int a = 0; a < 2; ++a)
    #pragma unroll
    for (int b = 0; b < 2; ++b)
      #pragma unroll
      for (int r = 0; r < 16; ++r) acc[a][b][r] = 0.f;

  #pragma unroll
  for (int ks = 0; ks < 8; ++ks) {
    v8bf af[2], bfg[2];
    int ch = ks * 2 + half;
    #pragma unroll
    for (int t = 0; t < 2; ++t) {
      int m = wm * 64 + t * 32 + l31;
      af[t] = *(const v8bf*)(As + m * 128 + ((ch ^ (m & 15)) << 3));
      int n = wn * 64 + t * 32 + l31;
      bfg[t] = *(const v8bf*)(Bs + n * 128 + ((ch ^ (n & 15)) << 3));
    }
    #pragma unroll
    for (int ti = 0; ti < 2; ++ti)
      #pragma unroll
      for (int tj = 0; tj < 2; ++tj)
        acc[ti][tj] = __builtin_amdgcn_mfma_f32_32x32x16_bf16(
            af[ti], bfg[tj], acc[ti][tj], 0, 0, 0);
  }

  __syncthreads();   // all As/Bs reads done; LDS reused for P

  // P[pair][c*32+d] = C * rnorm, bf16
  #pragma unroll
  for (int ti = 0; ti < 2; ++ti) {
    #pragma unroll
    for (int tj = 0; tj < 2; ++tj) {
      int il = wm * 2 + ti, jl = wn * 2 + tj;
      int p = il * 4 + jl;
      float rn = rnorm[(by * 4 + il) * NRES + (bx * 4 + jl)];
      #pragma unroll
      for (int r = 0; r < 16; ++r) {
        int cc = (r & 3) + 8 * (r >> 2) + 4 * half;   // c row
        Ps[p * 1032 + cc * 32 + l31] = (__bf16)(acc[ti][tj][r] * rn);
      }
    }
  }
  __syncthreads();

  // GEMM2: [16 x 1024] @ wot[z][cd]^T-layout -> [16 x 128]
  const int mr = lane & 15;   // pair row (A) / z col (B)
  const int kq = lane >> 4;   // k quad
  v4f acc2[2];
  #pragma unroll
  for (int t = 0; t < 2; ++t)
    #pragma unroll
    for (int r = 0; r < 4; ++r) acc2[t][r] = 0.f;

  #pragma unroll 4
  for (int kk = 0; kk < 32; ++kk) {
    v8bf a = *(const v8bf*)(Ps + mr * 1032 + kk * 32 + kq * 8);
    #pragma unroll
    for (int tn = 0; tn < 2; ++tn) {
      int z = wave * 32 + tn * 16 + mr;
      v8bf b = *(const v8bf*)(wot + z * 1024 + kk * 32 + kq * 8);
      acc2[tn] = __builtin_amdgcn_mfma_f32_16x16x32_bf16(a, b, acc2[tn], 0, 0, 0);
    }
  }

  #pragma unroll
  for (int tn = 0; tn < 2; ++tn) {
    int z = wave * 32 + tn * 16 + mr;
    float bz = bo[z];
    #pragma unroll
    for (int r = 0; r < 4; ++r) {
      int p = kq * 4 + r;
      int i = by * 4 + (p >> 2), j = bx * 4 + (p & 3);
      out[((size_t)i * NRES + j) * CZQ + z] = acc2[tn][r] + bz;
    }
  }
}

extern "C" void kernel_launch(void* const* d_in, const int* in_sizes, int n_in,
                              void* d_out, int out_size, void* d_ws, size_t ws_size,
                              hipStream_t stream) {
  const float* msa  = (const float*)d_in[0];
  const float* mask = (const float*)d_in[1];
  const float* lnw  = (const float*)d_in[2];
  const float* lnb  = (const float*)d_in[3];
  const float* wl   = (const float*)d_in[4];
  const float* bl   = (const float*)d_in[5];
  const float* wr   = (const float*)d_in[6];
  const float* br   = (const float*)d_in[7];
  const float* wo   = (const float*)d_in[8];
  const float* bo   = (const float*)d_in[9];
  float* out = (float*)d_out;

  char* ws = (char*)d_ws;
  __bf16* xh    = (__bf16*)(ws);                    // 16 MB
  __bf16* At    = (__bf16*)(ws + 16777216);         // 2 MB
  __bf16* Bt    = (__bf16*)(ws + 18874368);         // 2 MB
  float*  rnorm = (float*)(ws + 20971520);          // 256 KB
  __bf16* wot   = (__bf16*)(ws + 21233664);         // 256 KB
  __bf16* wcat  = (__bf16*)(ws + 21495808);         // 32 KB

  ln_kernel<<<8192, 256, 0, stream>>>(msa, lnw, lnb, xh);
  prep_kernel<<<832, 256, 0, stream>>>(mask, wo, wl, wr, rnorm, wot, wcat);
  proj_kernel<<<256, 256, 0, stream>>>(xh, wcat, bl, br, mask, At, Bt);
  outer_kernel<<<dim3(64, 64), 256, 0, stream>>>(At, Bt, rnorm, wot, bo, out);
}

// Round 2
// 193.072 us; speedup vs baseline: 1.3509x; 1.3509x over previous
//
#include <hip/hip_runtime.h>
#include <hip/hip_bf16.h>
#include <stdint.h>

#define C_INQ 256
#define CHQ 32
#define SDEP 128
#define NRES 256
#define CZQ 128

typedef __bf16 v8bf __attribute__((ext_vector_type(8)));
typedef __bf16 v4bf __attribute__((ext_vector_type(4)));
typedef float v16f __attribute__((ext_vector_type(16)));
typedef float v4f __attribute__((ext_vector_type(4)));

// ---------------- Kernel 1: LayerNorm -> xh_t[(i*128+s)][k] (bf16) ----
// one wave per (s,i) row; grid 8192 x 256
__global__ __launch_bounds__(256) void ln_kernel(
    const float* __restrict__ msa, const float* __restrict__ lnw,
    const float* __restrict__ lnb, __bf16* __restrict__ xh)
{
  const int wave = threadIdx.x >> 6, lane = threadIdx.x & 63;
  const int row = blockIdx.x * 4 + wave;          // s*256+i
  float4 x = ((const float4*)(msa + (size_t)row * C_INQ))[lane];
  float s1 = x.x + x.y + x.z + x.w;
  float s2 = x.x * x.x + x.y * x.y + x.z * x.z + x.w * x.w;
  #pragma unroll
  for (int o = 1; o < 64; o <<= 1) {
    s1 += __shfl_xor(s1, o);
    s2 += __shfl_xor(s2, o);
  }
  float mu = s1 * (1.f / 256.f);
  float var = s2 * (1.f / 256.f) - mu * mu;
  float rs = rsqrtf(var + 1e-5f);
  float4 w = ((const float4*)lnw)[lane];
  float4 b = ((const float4*)lnb)[lane];
  v4bf o;
  o[0] = (__bf16)((x.x - mu) * rs * w.x + b.x);
  o[1] = (__bf16)((x.y - mu) * rs * w.y + b.y);
  o[2] = (__bf16)((x.z - mu) * rs * w.z + b.z);
  o[3] = (__bf16)((x.w - mu) * rs * w.w + b.w);
  const int i = row & 255, s = row >> 8;
  *(v4bf*)(xh + ((size_t)i * SDEP + s) * C_INQ + lane * 4) = o;
}

// ---------------- Kernel 2: prep (rnorm, wo^T bf16, wl|wr ^T bf16) ----
// grid 832 x 256
__global__ __launch_bounds__(256) void prep_kernel(
    const float* __restrict__ mask, const float* __restrict__ wo,
    const float* __restrict__ wl, const float* __restrict__ wr,
    float* __restrict__ rnorm, __bf16* __restrict__ wot,
    __bf16* __restrict__ wcat)
{
  const int b = blockIdx.x, t = threadIdx.x;
  if (b < 256) {
    float acc = 0.f;
    for (int s = 0; s < SDEP; ++s)
      acc += mask[s * NRES + b] * mask[s * NRES + t];
    rnorm[b * NRES + t] = 1.f / fmaxf(acc, 1.f);
  } else if (b < 768) {
    int idx = (b - 256) * 256 + t;   // wot[z][cd] = wo[cd][z]
    int z = idx >> 10, cd = idx & 1023;
    wot[idx] = (__bf16)wo[cd * CZQ + z];
  } else {
    int idx = (b - 768) * 256 + t;   // wcat[n][k]
    int n = idx >> 8, k = idx & 255;
    const float* w = (n >= 32) ? wr : wl;
    wcat[idx] = (__bf16)w[k * CHQ + (n & 31)];
  }
}

// ---------------- Kernel 3: proj -> fragment-order At2/Bt2 -----------
// block = one i (256 blocks x 256 thr). wave w: s in [w*32,(w+1)*32).
// At2 element: At2[((i*16 + oct)*32 + c)*8 + (s&7)], oct = s>>3.
__global__ __launch_bounds__(256) void proj_kernel(
    const __bf16* __restrict__ xh, const __bf16* __restrict__ wcat,
    const float* __restrict__ bl, const float* __restrict__ br,
    const float* __restrict__ mask,
    __bf16* __restrict__ At2, __bf16* __restrict__ Bt2)
{
  __shared__ __bf16 Ls[4 * 64 * 36];
  const int i = blockIdx.x;
  const int w = threadIdx.x >> 6, lane = threadIdx.x & 63;
  const int half = lane >> 5, l31 = lane & 31;

  v16f acc0, acc1;
  #pragma unroll
  for (int r = 0; r < 16; ++r) { acc0[r] = 0.f; acc1[r] = 0.f; }

  const int s_row = w * 32 + l31;   // A-frag row
  const __bf16* ap = xh + ((size_t)i * SDEP + s_row) * C_INQ + half * 8;
  const __bf16* bp = wcat + l31 * 256 + half * 8;

  #pragma unroll
  for (int ks = 0; ks < 16; ++ks) {
    v8bf a  = *(const v8bf*)(ap + ks * 16);
    v8bf b0 = *(const v8bf*)(bp + ks * 16);
    v8bf b1 = *(const v8bf*)(bp + 32 * 256 + ks * 16);
    acc0 = __builtin_amdgcn_mfma_f32_32x32x16_bf16(a, b0, acc0, 0, 0, 0);
    acc1 = __builtin_amdgcn_mfma_f32_32x32x16_bf16(a, b1, acc1, 0, 0, 0);
  }

  // epilogue: bias + mask, write LDS transposed tile [n][s_local]
  __bf16* Lw = Ls + w * 64 * 36;
  const float bA = bl[l31], bB = br[l31];
  #pragma unroll
  for (int r = 0; r < 16; ++r) {
    int sl = (r & 3) + 8 * (r >> 2) + 4 * half;   // s_local (C/D row)
    float mv = mask[(w * 32 + sl) * NRES + i];
    Lw[l31 * 36 + sl]        = (__bf16)((acc0[r] + bA) * mv);   // n = c
    Lw[(32 + l31) * 36 + sl] = (__bf16)((acc1[r] + bB) * mv);   // n = 32+d
  }
  __syncthreads();

  // coalesced fragment-order stores: per oct, 64 lanes x 8B = 512B
  const int c = lane >> 1, jq = (lane & 1) * 4;
  #pragma unroll
  for (int o = 0; o < 4; ++o) {
    int oct = w * 4 + o;
    v4bf va = *(const v4bf*)(Lw + c * 36 + o * 8 + jq);
    v4bf vb = *(const v4bf*)(Lw + (32 + c) * 36 + o * 8 + jq);
    *(v4bf*)(At2 + ((size_t)i * 16 + oct) * 256 + lane * 4) = va;
    *(v4bf*)(Bt2 + ((size_t)i * 16 + oct) * 256 + lane * 4) = vb;
  }
}

// ---------------- Kernel 4: fused outer-product-mean + out proj ------
// tile 128x256 = (4 i) x (8 j), grid (32 j-tiles, 64 i-tiles) x 512 thr
__global__ __launch_bounds__(512, 4) void outer_kernel(
    const __bf16* __restrict__ At2, const __bf16* __restrict__ Bt2,
    const float* __restrict__ rnorm, const __bf16* __restrict__ wot,
    const float* __restrict__ bo, float* __restrict__ out)
{
  __shared__ __bf16 Ps[32 * 1032];
  const int tid = threadIdx.x;
  const int w = tid >> 6, lane = tid & 63;
  const int half = lane >> 5, l31 = lane & 31;
  const int bx = blockIdx.x;  // 8 j's
  const int by = blockIdx.y;  // 4 i's
  const int mt = w >> 1;      // i-local
  const int nh = w & 1;       // j half (4 j's)

  // GEMM1: direct-global fragment loads (coalesced 1KB/inst)
  const __bf16* Ap = At2 + ((size_t)(by * 4 + mt)) * 4096 + l31 * 8;
  const __bf16* Bp = Bt2 + ((size_t)(bx * 8 + nh * 4)) * 4096 + l31 * 8;

  v16f acc[4];
  #pragma unroll
  for (int t = 0; t < 4; ++t)
    #pragma unroll
    for (int r = 0; r < 16; ++r) acc[t][r] = 0.f;

  #pragma unroll
  for (int ks = 0; ks < 8; ++ks) {
    int off = (ks * 2 + half) * 256;
    v8bf a = *(const v8bf*)(Ap + off);
    #pragma unroll
    for (int t = 0; t < 4; ++t) {
      v8bf b = *(const v8bf*)(Bp + t * 4096 + off);
      acc[t] = __builtin_amdgcn_mfma_f32_32x32x16_bf16(a, b, acc[t], 0, 0, 0);
    }
  }

  // P[p][c*32+d] = outer * rnorm (bf16), p = i_local*8 + j_local
  #pragma unroll
  for (int t = 0; t < 4; ++t) {
    int jl = nh * 4 + t;
    int p = mt * 8 + jl;
    float rn = rnorm[(by * 4 + mt) * NRES + bx * 8 + jl];
    #pragma unroll
    for (int r = 0; r < 16; ++r) {
      int cc = (r & 3) + 8 * (r >> 2) + 4 * half;
      Ps[p * 1032 + cc * 32 + l31] = (__bf16)(acc[t][r] * rn);
    }
  }
  __syncthreads();

  // GEMM2: [32 x 1024] @ wot -> [32 x 128]; wave owns 16 z's, both m-tiles
  const int mr = lane & 15, kq = lane >> 4;
  const int z = w * 16 + mr;
  const __bf16* wp = wot + (size_t)z * 1024 + kq * 8;
  const __bf16* p0 = Ps + mr * 1032 + kq * 8;
  v4f acc2[2];
  #pragma unroll
  for (int t = 0; t < 2; ++t)
    #pragma unroll
    for (int r = 0; r < 4; ++r) acc2[t][r] = 0.f;

  #pragma unroll 8
  for (int kk = 0; kk < 32; ++kk) {
    v8bf b  = *(const v8bf*)(wp + kk * 32);
    v8bf a0 = *(const v8bf*)(p0 + kk * 32);
    v8bf a1 = *(const v8bf*)(p0 + 16 * 1032 + kk * 32);
    acc2[0] = __builtin_amdgcn_mfma_f32_16x16x32_bf16(a0, b, acc2[0], 0, 0, 0);
    acc2[1] = __builtin_amdgcn_mfma_f32_16x16x32_bf16(a1, b, acc2[1], 0, 0, 0);
  }

  const float bz = bo[z];
  #pragma unroll
  for (int mt2 = 0; mt2 < 2; ++mt2) {
    #pragma unroll
    for (int r = 0; r < 4; ++r) {
      int p = mt2 * 16 + kq * 4 + r;
      int i = by * 4 + (p >> 3), j = bx * 8 + (p & 7);
      out[((size_t)i * NRES + j) * CZQ + z] = acc2[mt2][r] + bz;
    }
  }
}

extern "C" void kernel_launch(void* const* d_in, const int* in_sizes, int n_in,
                              void* d_out, int out_size, void* d_ws, size_t ws_size,
                              hipStream_t stream) {
  const float* msa  = (const float*)d_in[0];
  const float* mask = (const float*)d_in[1];
  const float* lnw  = (const float*)d_in[2];
  const float* lnb  = (const float*)d_in[3];
  const float* wl   = (const float*)d_in[4];
  const float* bl   = (const float*)d_in[5];
  const float* wr   = (const float*)d_in[6];
  const float* br   = (const float*)d_in[7];
  const float* wo   = (const float*)d_in[8];
  const float* bo   = (const float*)d_in[9];
  float* out = (float*)d_out;

  char* ws = (char*)d_ws;
  __bf16* xh    = (__bf16*)(ws);                    // 16 MB
  __bf16* At2   = (__bf16*)(ws + 16777216);         // 2 MB
  __bf16* Bt2   = (__bf16*)(ws + 18874368);         // 2 MB
  float*  rnorm = (float*)(ws + 20971520);          // 256 KB
  __bf16* wot   = (__bf16*)(ws + 21233664);         // 256 KB
  __bf16* wcat  = (__bf16*)(ws + 21495808);         // 32 KB

  ln_kernel<<<8192, 256, 0, stream>>>(msa, lnw, lnb, xh);
  prep_kernel<<<832, 256, 0, stream>>>(mask, wo, wl, wr, rnorm, wot, wcat);
  proj_kernel<<<256, 256, 0, stream>>>(xh, wcat, bl, br, mask, At2, Bt2);
  outer_kernel<<<dim3(32, 64), 512, 0, stream>>>(At2, Bt2, rnorm, wot, bo, out);
}

// Round 3
// 159.773 us; speedup vs baseline: 1.6325x; 1.2084x over previous
//
#include <hip/hip_runtime.h>
#include <hip/hip_bf16.h>
#include <stdint.h>

#define SDEP 128
#define NRES 256
#define CZQ 128

typedef __bf16 v8bf __attribute__((ext_vector_type(8)));
typedef __bf16 v4bf __attribute__((ext_vector_type(4)));
typedef float v16f __attribute__((ext_vector_type(16)));
typedef float v4f __attribute__((ext_vector_type(4)));

// full-wave sum via DPP (VALU pipe, no LDS). Result valid in lane 63.
__device__ __forceinline__ float dpp_wave_sum(float x) {
  float t;
#define STEP(ctrl)                                                         \
  t = __builtin_bit_cast(float, __builtin_amdgcn_update_dpp(               \
          0, __builtin_bit_cast(int, x), ctrl, 0xF, 0xF, true));           \
  x += t;
  STEP(0x111)  // row_shr:1
  STEP(0x112)  // row_shr:2
  STEP(0x114)  // row_shr:4
  STEP(0x118)  // row_shr:8   -> lane15 of each row16 has row sum
  STEP(0x142)  // row_bcast15 -> lane31 = sum(0..31), lane63 = sum(32..63)
  STEP(0x143)  // row_bcast31 -> lane63 = sum(0..63)
#undef STEP
  return x;
}
__device__ __forceinline__ float lane63(float x) {
  return __builtin_bit_cast(float,
      __builtin_amdgcn_readlane(__builtin_bit_cast(int, x), 63));
}

// ---------------- Kernel 1: prep (rnorm, wot3, wcat2) ----------------
// grid 832 x 256
// wot3[((w*32+kk)*16+n)*32 + kq*8+j] = wo[(kk*32+kq*8+j)*128 + (w*16+n)]
// wcat2[((tile*16+ks)*2+half)*256 + n*8+j] = w{l,r}[(ks*16+half*8+j)*32 + n]
__global__ __launch_bounds__(256) void prep_kernel(
    const float* __restrict__ mask, const float* __restrict__ wo,
    const float* __restrict__ wl, const float* __restrict__ wr,
    float* __restrict__ rnorm, __bf16* __restrict__ wot3,
    __bf16* __restrict__ wcat2)
{
  const int b = blockIdx.x, t = threadIdx.x;
  if (b < 256) {
    float acc = 0.f;
    for (int s = 0; s < SDEP; ++s)
      acc += mask[s * NRES + b] * mask[s * NRES + t];
    rnorm[b * NRES + t] = 1.f / fmaxf(acc, 1.f);
  } else if (b < 768) {
    int idx = (b - 256) * 256 + t;
    int q = idx & 31, n = (idx >> 5) & 15, kk = (idx >> 9) & 31, wv = idx >> 14;
    wot3[idx] = (__bf16)wo[(kk * 32 + q) * CZQ + wv * 16 + n];
  } else {
    int idx = (b - 768) * 256 + t;
    int j = idx & 7, n = (idx >> 3) & 31, hf = (idx >> 8) & 1;
    int ks = (idx >> 9) & 15, tile = idx >> 13;
    int k = ks * 16 + hf * 8 + j;
    const float* w = tile ? wr : wl;
    wcat2[idx] = (__bf16)w[k * 32 + n];
  }
}

// ---------------- Kernel 2: fused LayerNorm + projections ------------
// block = one i (256 blocks x 256 thr). wave w owns rows s in [w*32,(w+1)*32).
// Emits fragment-order At2/Bt2: At2[i*4096 + oct*256 + c*8 + (s&7)], oct=s>>3.
__global__ __launch_bounds__(256, 1) void projln_kernel(
    const float* __restrict__ msa, const float* __restrict__ lnw,
    const float* __restrict__ lnb, const __bf16* __restrict__ wcat2,
    const float* __restrict__ bl, const float* __restrict__ br,
    const float* __restrict__ mask,
    __bf16* __restrict__ At2, __bf16* __restrict__ Bt2)
{
  __shared__ __bf16 xs[128 * 258];     // 258 = 256 + 2 pad (odd word stride)
  __shared__ __bf16 Ls[4 * 64 * 36];
  const int i = blockIdx.x;
  const int w = threadIdx.x >> 6, lane = threadIdx.x & 63;
  const int half = lane >> 5, l31 = lane & 31;

  const float4 wv = ((const float4*)lnw)[lane];
  const float4 bv = ((const float4*)lnb)[lane];

  // ---- Phase 1: LN of this wave's 32 rows into LDS (wave-private) ----
  #pragma unroll 4
  for (int r = 0; r < 32; ++r) {
    const int s = w * 32 + r;
    float4 x = ((const float4*)(msa + ((size_t)s * 256 + i) * 256))[lane];
    float s1 = dpp_wave_sum(x.x + x.y + x.z + x.w);
    float s2 = dpp_wave_sum(x.x * x.x + x.y * x.y + x.z * x.z + x.w * x.w);
    float mu = lane63(s1) * (1.f / 256.f);
    float var = lane63(s2) * (1.f / 256.f) - mu * mu;
    float rs = rsqrtf(var + 1e-5f);
    v4bf o;
    o[0] = (__bf16)((x.x - mu) * rs * wv.x + bv.x);
    o[1] = (__bf16)((x.y - mu) * rs * wv.y + bv.y);
    o[2] = (__bf16)((x.z - mu) * rs * wv.z + bv.z);
    o[3] = (__bf16)((x.w - mu) * rs * wv.w + bv.w);
    *(v4bf*)(xs + s * 258 + lane * 4) = o;
  }
  // no barrier: MFMA phase reads only this wave's own rows

  // ---- Phase 2: [32 s-rows x 256k] @ wcat2 -> acc (MFMA) ----
  v16f acc0, acc1;
  #pragma unroll
  for (int r = 0; r < 16; ++r) { acc0[r] = 0.f; acc1[r] = 0.f; }

  const __bf16* xrow = xs + (w * 32 + l31) * 258 + half * 8;
  const __bf16* bbase = wcat2 + half * 256 + l31 * 8;
  #pragma unroll
  for (int ks = 0; ks < 16; ++ks) {
    v8bf a  = *(const v8bf*)(xrow + ks * 16);
    v8bf b0 = *(const v8bf*)(bbase + ks * 512);
    v8bf b1 = *(const v8bf*)(bbase + 8192 + ks * 512);
    acc0 = __builtin_amdgcn_mfma_f32_32x32x16_bf16(a, b0, acc0, 0, 0, 0);
    acc1 = __builtin_amdgcn_mfma_f32_32x32x16_bf16(a, b1, acc1, 0, 0, 0);
  }

  // ---- Epilogue: bias+mask, transpose via wave-private LDS tile ----
  __bf16* Lw = Ls + w * 64 * 36;
  const float bA = bl[l31], bB = br[l31];
  #pragma unroll
  for (int r = 0; r < 16; ++r) {
    int sl = (r & 3) + 8 * (r >> 2) + 4 * half;   // s_local
    float mv = mask[(w * 32 + sl) * NRES + i];
    Lw[l31 * 36 + sl]        = (__bf16)((acc0[r] + bA) * mv);
    Lw[(32 + l31) * 36 + sl] = (__bf16)((acc1[r] + bB) * mv);
  }
  // wave-private write->read; compiler inserts lgkmcnt waits

  const int c = lane >> 1, jq = (lane & 1) * 4;
  #pragma unroll
  for (int o = 0; o < 4; ++o) {
    int oct = w * 4 + o;
    v4bf va = *(const v4bf*)(Lw + c * 36 + o * 8 + jq);
    v4bf vb = *(const v4bf*)(Lw + (32 + c) * 36 + o * 8 + jq);
    *(v4bf*)(At2 + ((size_t)i * 16 + oct) * 256 + lane * 4) = va;
    *(v4bf*)(Bt2 + ((size_t)i * 16 + oct) * 256 + lane * 4) = vb;
  }
}

// ---------------- Kernel 3: fused outer-product-mean + out proj ------
// tile 128x256 = (4 i) x (8 j), grid (32 j-tiles, 64 i-tiles) x 512 thr
__global__ __launch_bounds__(512, 4) void outer_kernel(
    const __bf16* __restrict__ At2, const __bf16* __restrict__ Bt2,
    const float* __restrict__ rnorm, const __bf16* __restrict__ wot3,
    const float* __restrict__ bo, float* __restrict__ out)
{
  __shared__ __bf16 Ps[32 * 1032];
  const int tid = threadIdx.x;
  const int w = tid >> 6, lane = tid & 63;
  const int half = lane >> 5, l31 = lane & 31;
  const int bx = blockIdx.x;  // 8 j's
  const int by = blockIdx.y;  // 4 i's
  const int mt = w >> 1;      // i-local
  const int nh = w & 1;       // j half (4 j's)

  // GEMM1: direct-global fragment loads (contiguous 1KB per inst)
  const __bf16* Ap = At2 + ((size_t)(by * 4 + mt)) * 4096 + l31 * 8;
  const __bf16* Bp = Bt2 + ((size_t)(bx * 8 + nh * 4)) * 4096 + l31 * 8;

  v16f acc[4];
  #pragma unroll
  for (int t = 0; t < 4; ++t)
    #pragma unroll
    for (int r = 0; r < 16; ++r) acc[t][r] = 0.f;

  #pragma unroll
  for (int ks = 0; ks < 8; ++ks) {
    int off = (ks * 2 + half) * 256;
    v8bf a = *(const v8bf*)(Ap + off);
    #pragma unroll
    for (int t = 0; t < 4; ++t) {
      v8bf b = *(const v8bf*)(Bp + t * 4096 + off);
      acc[t] = __builtin_amdgcn_mfma_f32_32x32x16_bf16(a, b, acc[t], 0, 0, 0);
    }
  }

  // P[p][c*32+d] = outer * rnorm (bf16), p = i_local*8 + j_local
  #pragma unroll
  for (int t = 0; t < 4; ++t) {
    int jl = nh * 4 + t;
    int p = mt * 8 + jl;
    float rn = rnorm[(by * 4 + mt) * NRES + bx * 8 + jl];
    #pragma unroll
    for (int r = 0; r < 16; ++r) {
      int cc = (r & 3) + 8 * (r >> 2) + 4 * half;
      Ps[p * 1032 + cc * 32 + l31] = (__bf16)(acc[t][r] * rn);
    }
  }
  __syncthreads();

  // GEMM2: [32 x 1024] @ wot3 -> [32 x 128]; wave owns 16 z's.
  // wot3 loads are fully coalesced 1KB per (w,kk).
  const int mr = lane & 15, kq = lane >> 4;
  const int z = w * 16 + mr;
  const __bf16* wp = wot3 + (size_t)w * 16384 + mr * 32 + kq * 8;
  const __bf16* p0 = Ps + mr * 1032 + kq * 8;
  v4f acc2[2];
  #pragma unroll
  for (int t = 0; t < 2; ++t)
    #pragma unroll
    for (int r = 0; r < 4; ++r) acc2[t][r] = 0.f;

  #pragma unroll 8
  for (int kk = 0; kk < 32; ++kk) {
    v8bf b  = *(const v8bf*)(wp + kk * 512);
    v8bf a0 = *(const v8bf*)(p0 + kk * 32);
    v8bf a1 = *(const v8bf*)(p0 + 16 * 1032 + kk * 32);
    acc2[0] = __builtin_amdgcn_mfma_f32_16x16x32_bf16(a0, b, acc2[0], 0, 0, 0);
    acc2[1] = __builtin_amdgcn_mfma_f32_16x16x32_bf16(a1, b, acc2[1], 0, 0, 0);
  }

  const float bz = bo[z];
  #pragma unroll
  for (int mt2 = 0; mt2 < 2; ++mt2) {
    #pragma unroll
    for (int r = 0; r < 4; ++r) {
      int p = mt2 * 16 + kq * 4 + r;
      int i = by * 4 + (p >> 3), j = bx * 8 + (p & 7);
      out[((size_t)i * NRES + j) * CZQ + z] = acc2[mt2][r] + bz;
    }
  }
}

extern "C" void kernel_launch(void* const* d_in, const int* in_sizes, int n_in,
                              void* d_out, int out_size, void* d_ws, size_t ws_size,
                              hipStream_t stream) {
  const float* msa  = (const float*)d_in[0];
  const float* mask = (const float*)d_in[1];
  const float* lnw  = (const float*)d_in[2];
  const float* lnb  = (const float*)d_in[3];
  const float* wl   = (const float*)d_in[4];
  const float* bl   = (const float*)d_in[5];
  const float* wr   = (const float*)d_in[6];
  const float* br   = (const float*)d_in[7];
  const float* wo   = (const float*)d_in[8];
  const float* bo   = (const float*)d_in[9];
  float* out = (float*)d_out;

  char* ws = (char*)d_ws;
  __bf16* At2   = (__bf16*)(ws);                    // 2 MB
  __bf16* Bt2   = (__bf16*)(ws + 2097152);          // 2 MB
  float*  rnorm = (float*)(ws + 4194304);           // 256 KB
  __bf16* wot3  = (__bf16*)(ws + 4456448);          // 256 KB
  __bf16* wcat2 = (__bf16*)(ws + 4718592);          // 32 KB

  prep_kernel<<<832, 256, 0, stream>>>(mask, wo, wl, wr, rnorm, wot3, wcat2);
  projln_kernel<<<256, 256, 0, stream>>>(msa, lnw, lnb, wcat2, bl, br, mask,
                                         At2, Bt2);
  outer_kernel<<<dim3(32, 64), 512, 0, stream>>>(At2, Bt2, rnorm, wot3, bo, out);
}